// Round 6
// baseline (364.318 us; speedup 1.0000x reference)
//
#include <hip/hip_runtime.h>
#include <hip/hip_cooperative_groups.h>
#include <math.h>

namespace cg = cooperative_groups;

// (B,N,D,H) = (4, 2048, 1024, 64)
constexpr int kN = 2048;
constexpr int kD = 1024;
constexpr int SMEM_BYTES = 60416;   // max over phases (qkv: 59904)

typedef __attribute__((ext_vector_type(8))) short bf16x8;
typedef __attribute__((ext_vector_type(4))) short bf16x4;
typedef __attribute__((ext_vector_type(4))) float f32x4;

#define MFMA(a, b, c) __builtin_amdgcn_mfma_f32_16x16x32_bf16(a, b, c, 0, 0, 0)

__device__ __forceinline__ short f2bf(float f) {
    unsigned u = __float_as_uint(f);
    u += 0x7fff + ((u >> 16) & 1);      // round-to-nearest-even
    return (short)(u >> 16);
}

// global->LDS direct DMA. LDS dest = wave-uniform base + lane*16.
__device__ __forceinline__ void g2l(void* lds, const void* g, int nbytes, int t) {
    int lane = t & 63, w = t >> 6;
    for (int base = w * 1024; base < nbytes; base += 4096) {
        if (base + lane * 16 < nbytes) {
            __builtin_amdgcn_global_load_lds(
                (const __attribute__((address_space(1))) void*)((const char*)g + base + lane * 16),
                (__attribute__((address_space(3))) void*)((char*)lds + base),
                16, 0, 0);
        }
    }
}

// ===========================================================================
// Phase bodies (shared by fused cooperative kernel and standalone fallback).
// All written for a 512-block x 256-thread grid.
// ===========================================================================

// prep: Wt[kc][192][72] = bf16(W^T), bcat = bq|bk|bv
__device__ __forceinline__ void phase_prep(int blk, int t,
        const float* __restrict__ Wq, const float* __restrict__ Wk,
        const float* __restrict__ Wv, const float* __restrict__ bq,
        const float* __restrict__ bk, const float* __restrict__ bv,
        short* __restrict__ Wt, float* __restrict__ bcat)
{
    int tid = blk * 256 + t;
    for (int e = tid; e < 16 * 192 * 72; e += 512 * 256) {
        int kc = e / (192 * 72);
        int rem = e - kc * (192 * 72);
        int n = rem / 72, c = rem - n * 72;
        short v = 0;
        if (c < 64) {
            int d = kc * 64 + c;
            float wv = (n < 64) ? Wq[d * 64 + n]
                     : (n < 128) ? Wk[d * 64 + (n - 64)]
                     : Wv[d * 64 + (n - 128)];
            v = f2bf(wv);
        }
        Wt[e] = v;
    }
    if (tid < 192)
        bcat[tid] = (tid < 64) ? bq[tid] : (tid < 128) ? bk[tid - 64] : bv[tid - 128];
}

// qkv: 512 blocks x 16 rows; wave w = cols [48w,48w+48). x fp32 direct
// (prefetch 2 deep), W double-buffered g2l.
__device__ __forceinline__ void phase_qkv(int blk, int t, char* smem,
        const float* __restrict__ x, const short* __restrict__ Wt,
        const float* __restrict__ bcat,
        short* __restrict__ gq, short* __restrict__ gk, short* __restrict__ vt)
{
    short* wsm = (short*)smem;                 // [2][192*72]  55296 B
    short* xs  = (short*)(smem + 55296);       // [2][16*72]    4608 B
    const int w = t >> 6, lane = t & 63, l15 = lane & 15, q8 = lane >> 4;
    const int m0 = blk * 16;
    const int xrow = t >> 4, xc4 = t & 15;
    const float* xbase = x + (size_t)(m0 + xrow) * kD + xc4 * 4;

    f32x4 acc[3];
    #pragma unroll
    for (int ct = 0; ct < 3; ++ct) acc[ct] = (f32x4){0.f, 0.f, 0.f, 0.f};

    float4 xcur = *(const float4*)(xbase);
    g2l(wsm, Wt, 192 * 144, t);
    {
        bf16x4 pk = {f2bf(xcur.x), f2bf(xcur.y), f2bf(xcur.z), f2bf(xcur.w)};
        *(bf16x4*)&xs[xrow * 72 + xc4 * 4] = pk;
    }
    float4 xnxt = *(const float4*)(xbase + 64);
    __syncthreads();

    for (int kc = 0; kc < 16; ++kc) {
        const int cur = kc & 1, nb = cur ^ 1;
        if (kc < 15)
            g2l(wsm + nb * 13824, Wt + (size_t)(kc + 1) * 192 * 72, 192 * 144, t);

        bf16x8 a0 = *(const bf16x8*)&xs[cur * 1152 + l15 * 72 + q8 * 8];
        bf16x8 a1 = *(const bf16x8*)&xs[cur * 1152 + l15 * 72 + 32 + q8 * 8];
        #pragma unroll
        for (int ct = 0; ct < 3; ++ct) {
            int brow = w * 48 + ct * 16 + l15;
            bf16x8 b0 = *(const bf16x8*)&wsm[cur * 13824 + brow * 72 + q8 * 8];
            bf16x8 b1 = *(const bf16x8*)&wsm[cur * 13824 + brow * 72 + 32 + q8 * 8];
            acc[ct] = MFMA(a0, b0, acc[ct]);
            acc[ct] = MFMA(a1, b1, acc[ct]);
        }
        if (kc < 15) {
            bf16x4 pk = {f2bf(xnxt.x), f2bf(xnxt.y), f2bf(xnxt.z), f2bf(xnxt.w)};
            *(bf16x4*)&xs[nb * 1152 + xrow * 72 + xc4 * 4] = pk;
            if (kc < 14)
                xnxt = *(const float4*)(xbase + (kc + 2) * 64);
        }
        __syncthreads();
    }

    const int bz = m0 >> 11;
    const int jt = (m0 & 2047) >> 6;
    const int jb = m0 & 63;
    #pragma unroll
    for (int ct = 0; ct < 3; ++ct) {
        int nb2 = w * 48 + ct * 16;
        int n = nb2 + l15;
        float bias = bcat[n];
        if (nb2 < 64) {
            #pragma unroll
            for (int r = 0; r < 4; ++r)
                gq[(size_t)(m0 + q8 * 4 + r) * 72 + n] = f2bf(acc[ct][r] + bias);
        } else if (nb2 < 128) {
            #pragma unroll
            for (int r = 0; r < 4; ++r)
                gk[(size_t)(m0 + q8 * 4 + r) * 72 + (n - 64)] = f2bf(acc[ct][r] + bias);
        } else {
            int h = n - 128;
            bf16x4 pk = {f2bf(acc[ct][0] + bias), f2bf(acc[ct][1] + bias),
                         f2bf(acc[ct][2] + bias), f2bf(acc[ct][3] + bias)};
            *(bf16x4*)&vt[((size_t)((bz * 32 + jt) * 64 + h)) * 72 + jb + q8 * 4] = pk;
        }
    }
}

// stats: l[j] = sum_{i>=j, s!=0} exp(s/8). k-tiles double-buffered.
__device__ __forceinline__ void phase_stats(int blk, int t, char* smem,
        const short* __restrict__ gq, const short* __restrict__ gk,
        float* __restrict__ l2)
{
    short* qsm = (short*)smem;                 // [64*72]   9216 B
    short* ksm = (short*)(smem + 9216);        // [2][64*72] 18432 B
    const int w = t >> 6, lane = t & 63, l15 = lane & 15, q8 = lane >> 4;
    const int ic = blk & 3, bz = (blk >> 2) & 3, jt = blk >> 4;
    const int j0 = jt * 64;
    const int ilo = ic * 512, ihi = ilo + 512;
    const int istart = (j0 > ilo) ? j0 : ilo;
    const int count = (istart < ihi) ? ((ihi - istart) >> 6) : 0;

    float lloc[4] = {0.f, 0.f, 0.f, 0.f};

    if (count > 0) {
        g2l(qsm, gq + (size_t)(bz * kN + j0) * 72, 64 * 144, t);
        g2l(ksm, gk + (size_t)(bz * kN + istart) * 72, 64 * 144, t);
        __syncthreads();
        int jrow = 16 * w + l15;
        bf16x8 a0 = *(const bf16x8*)&qsm[jrow * 72 + q8 * 8];
        bf16x8 a1 = *(const bf16x8*)&qsm[jrow * 72 + 32 + q8 * 8];

        for (int idx = 0; idx < count; ++idx) {
            const int cur = idx & 1;
            if (idx + 1 < count)
                g2l(ksm + (cur ^ 1) * 4608,
                    gk + (size_t)(bz * kN + istart + (idx + 1) * 64) * 72, 64 * 144, t);
            const int i0 = istart + idx * 64;
            #pragma unroll
            for (int it = 0; it < 4; ++it) {
                int irow = it * 16 + l15;
                bf16x8 b0 = *(const bf16x8*)&ksm[cur * 4608 + irow * 72 + q8 * 8];
                bf16x8 b1 = *(const bf16x8*)&ksm[cur * 4608 + irow * 72 + 32 + q8 * 8];
                f32x4 s = (f32x4){0.f, 0.f, 0.f, 0.f};
                s = MFMA(a0, b0, s);
                s = MFMA(a1, b1, s);
                int ig = i0 + it * 16 + l15;
                #pragma unroll
                for (int r = 0; r < 4; ++r) {
                    int jg = j0 + 16 * w + q8 * 4 + r;
                    float sv = s[r];
                    float e = __expf(sv * 0.125f);
                    lloc[r] += ((ig >= jg) && (sv != 0.0f)) ? e : 0.0f;
                }
            }
            __syncthreads();
        }
    }
    #pragma unroll
    for (int off = 1; off < 16; off <<= 1)
        #pragma unroll
        for (int r = 0; r < 4; ++r)
            lloc[r] += __shfl_xor(lloc[r], off);
    if (l15 == 0) {
        #pragma unroll
        for (int r = 0; r < 4; ++r)
            l2[ic * 8192 + bz * kN + j0 + 16 * w + q8 * 4 + r] = lloc[r];
    }
}

// out: partial[i,h] = sum_{j in jc-chunk, j<=i} exp(s/8)*(1/l[j])*v[j,h]
// combine fused (l2 4-chunk sum); q/v/r double-buffered; S identical to stats.
__device__ __forceinline__ void phase_out(int blk, int t, char* smem,
        const short* __restrict__ gq, const short* __restrict__ gk,
        const short* __restrict__ vt, const float* __restrict__ l2,
        float* __restrict__ part)
{
    short* ksm = (short*)smem;                 // [64*72]    9216 B
    short* qsm = (short*)(smem + 9216);        // [2][64*72] 18432 B
    short* vsm = (short*)(smem + 27648);       // [2][64*72] 18432 B
    short* psm = (short*)(smem + 46080);       // [64*72]    9216 B
    float* rsm = (float*)(smem + 55296);       // [2][64]      512 B
    const int w = t >> 6, lane = t & 63, l15 = lane & 15, q8 = lane >> 4;
    const int jc = blk & 3, bz = (blk >> 2) & 3, it = blk >> 4;
    const int i0 = it * 64;
    const int jlo = jc * 512;
    const int jhi = (jlo + 512 < i0 + 64) ? (jlo + 512) : (i0 + 64);
    const int count = (jlo < jhi) ? ((jhi - jlo) >> 6) : 0;

    f32x4 oacc[4];
    #pragma unroll
    for (int i = 0; i < 4; ++i) oacc[i] = (f32x4){0.f, 0.f, 0.f, 0.f};

    if (count > 0) {
        g2l(ksm, gk + (size_t)(bz * kN + i0) * 72, 64 * 144, t);
        g2l(qsm, gq + (size_t)(bz * kN + jlo) * 72, 64 * 144, t);
        g2l(vsm, vt + (size_t)((bz * 32 + (jlo >> 6)) * 64) * 72, 64 * 144, t);
        if (t < 64) {
            int j = bz * kN + jlo + t;
            float l = l2[j] + l2[8192 + j] + l2[16384 + j] + l2[24576 + j];
            rsm[t] = (l > 0.f) ? 1.0f / l : 0.0f;
        }
        __syncthreads();

        for (int idx = 0; idx < count; ++idx) {
            const int cur = idx & 1, nb = cur ^ 1;
            const int j0s = jlo + idx * 64;
            if (idx + 1 < count) {
                g2l(qsm + nb * 4608, gq + (size_t)(bz * kN + j0s + 64) * 72, 64 * 144, t);
                g2l(vsm + nb * 4608,
                    vt + (size_t)((bz * 32 + ((j0s + 64) >> 6)) * 64) * 72, 64 * 144, t);
                if (t < 64) {
                    int j = bz * kN + j0s + 64 + t;
                    float l = l2[j] + l2[8192 + j] + l2[16384 + j] + l2[24576 + j];
                    rsm[nb * 64 + t] = (l > 0.f) ? 1.0f / l : 0.0f;
                }
            }
            // S phase (identical sequence to stats)
            int jrow = 16 * w + l15;
            bf16x8 a0 = *(const bf16x8*)&qsm[cur * 4608 + jrow * 72 + q8 * 8];
            bf16x8 a1 = *(const bf16x8*)&qsm[cur * 4608 + jrow * 72 + 32 + q8 * 8];
            #pragma unroll
            for (int itile = 0; itile < 4; ++itile) {
                int irow = itile * 16 + l15;
                bf16x8 b0 = *(const bf16x8*)&ksm[irow * 72 + q8 * 8];
                bf16x8 b1 = *(const bf16x8*)&ksm[irow * 72 + 32 + q8 * 8];
                f32x4 sv4 = (f32x4){0.f, 0.f, 0.f, 0.f};
                sv4 = MFMA(a0, b0, sv4);
                sv4 = MFMA(a1, b1, sv4);
                int ig = i0 + itile * 16 + l15;
                bf16x4 pk;
                #pragma unroll
                for (int r = 0; r < 4; ++r) {
                    int jl = 16 * w + q8 * 4 + r;
                    int jg = j0s + jl;
                    float sv = sv4[r];
                    float p = ((ig >= jg) && (sv != 0.0f))
                            ? __expf(sv * 0.125f) * rsm[cur * 64 + jl] : 0.0f;
                    pk[r] = f2bf(p);
                }
                *(bf16x4*)&psm[(itile * 16 + l15) * 72 + 16 * w + q8 * 4] = pk;
            }
            __syncthreads();

            // PV phase: A = psm[i-local][j], B = vsm[h][j]
            bf16x8 pa0 = *(const bf16x8*)&psm[(16 * w + l15) * 72 + q8 * 8];
            bf16x8 pa1 = *(const bf16x8*)&psm[(16 * w + l15) * 72 + 32 + q8 * 8];
            #pragma unroll
            for (int ht = 0; ht < 4; ++ht) {
                int vrow = ht * 16 + l15;
                bf16x8 vb0 = *(const bf16x8*)&vsm[cur * 4608 + vrow * 72 + q8 * 8];
                bf16x8 vb1 = *(const bf16x8*)&vsm[cur * 4608 + vrow * 72 + 32 + q8 * 8];
                oacc[ht] = MFMA(pa0, vb0, oacc[ht]);
                oacc[ht] = MFMA(pa1, vb1, oacc[ht]);
            }
            __syncthreads();
        }
    }
    size_t base = ((size_t)(jc * 4 + bz) * kN + i0) * 64;
    #pragma unroll
    for (int ht = 0; ht < 4; ++ht)
        #pragma unroll
        for (int r = 0; r < 4; ++r)
            part[base + (size_t)(16 * w + q8 * 4 + r) * 64 + ht * 16 + l15] = oacc[ht][r];
}

// reduce: out = sum of 4 jc-chunk partials. 512*256 threads = 1 float4 each.
__device__ __forceinline__ void phase_reduce(int blk, int t,
        const float* __restrict__ part, float* __restrict__ out)
{
    int idx = blk * 256 + t;                   // 0..131071
    const float4* p = (const float4*)part;
    float4 a = p[idx];
    float4 b = p[idx + 131072];
    float4 c = p[idx + 262144];
    float4 d = p[idx + 393216];
    float4 r;
    r.x = a.x + b.x + c.x + d.x;
    r.y = a.y + b.y + c.y + d.y;
    r.z = a.z + b.z + c.z + d.z;
    r.w = a.w + b.w + c.w + d.w;
    ((float4*)out)[idx] = r;
}

// ===========================================================================
// Fused cooperative kernel: all phases, grid.sync() between.
// grid 512 x 256, LDS 60416 -> 2 blocks/CU co-resident on 256 CUs.
// ===========================================================================
__global__ __launch_bounds__(256, 2) void fused_kernel(
        const float* x, const float* Wq, const float* bq, const float* Wk,
        const float* bk, const float* Wv, const float* bv, float* out,
        short* Wt, float* bcat, short* gq, short* gk, short* vt,
        float* l2, float* part)
{
    __shared__ __align__(16) char smem[SMEM_BYTES];
    cg::grid_group grid = cg::this_grid();
    const int blk = blockIdx.x, t = threadIdx.x;
    phase_prep(blk, t, Wq, Wk, Wv, bq, bk, bv, Wt, bcat);
    grid.sync();
    phase_qkv(blk, t, smem, x, Wt, bcat, gq, gk, vt);
    grid.sync();
    phase_stats(blk, t, smem, gq, gk, l2);
    grid.sync();
    phase_out(blk, t, smem, gq, gk, vt, l2, part);
    grid.sync();
    phase_reduce(blk, t, part, out);
}

// ===========================================================================
// Standalone fallback kernels (round-4 structure)
// ===========================================================================
__global__ __launch_bounds__(256) void prep_kernel(
        const float* __restrict__ Wq, const float* __restrict__ Wk,
        const float* __restrict__ Wv, const float* __restrict__ bq,
        const float* __restrict__ bk, const float* __restrict__ bv,
        short* __restrict__ Wt, float* __restrict__ bcat)
{
    phase_prep(blockIdx.x, threadIdx.x, Wq, Wk, Wv, bq, bk, bv, Wt, bcat);
}

__global__ __launch_bounds__(256) void qkv_kernel(
        const float* __restrict__ x, const short* __restrict__ Wt,
        const float* __restrict__ bcat,
        short* __restrict__ gq, short* __restrict__ gk, short* __restrict__ vt)
{
    __shared__ __align__(16) char smem[SMEM_BYTES];
    phase_qkv(blockIdx.x, threadIdx.x, smem, x, Wt, bcat, gq, gk, vt);
}

__global__ __launch_bounds__(256) void stats_kernel(
        const short* __restrict__ gq, const short* __restrict__ gk,
        float* __restrict__ l2)
{
    __shared__ __align__(16) char smem[SMEM_BYTES];
    phase_stats(blockIdx.x, threadIdx.x, smem, gq, gk, l2);
}

__global__ __launch_bounds__(256) void out_kernel(
        const short* __restrict__ gq, const short* __restrict__ gk,
        const short* __restrict__ vt, const float* __restrict__ l2,
        float* __restrict__ part)
{
    __shared__ __align__(16) char smem[SMEM_BYTES];
    phase_out(blockIdx.x, threadIdx.x, smem, gq, gk, vt, l2, part);
}

__global__ __launch_bounds__(256) void reduce_kernel(
        const float* __restrict__ part, float* __restrict__ out)
{
    phase_reduce(blockIdx.x, threadIdx.x, part, out);
}

extern "C" void kernel_launch(void* const* d_in, const int* in_sizes, int n_in,
                              void* d_out, int out_size, void* d_ws, size_t ws_size,
                              hipStream_t stream)
{
    const float* x  = (const float*)d_in[0];
    const float* Wq = (const float*)d_in[1];
    const float* bq = (const float*)d_in[2];
    const float* Wk = (const float*)d_in[3];
    const float* bk = (const float*)d_in[4];
    const float* Wv = (const float*)d_in[5];
    const float* bv = (const float*)d_in[6];
    float* out = (float*)d_out;

    char* base = (char*)d_ws;
    short* Wt   = (short*)(base);                    //    442,368 B
    float* bcat = (float*)(base + 442368);           //      1,024 B
    short* gq   = (short*)(base + 443392);           //  1,179,648 B
    short* gk   = (short*)(base + 1623040);          //  1,179,648 B
    short* vt   = (short*)(base + 2802688);          //  1,179,648 B
    float* l2   = (float*)(base + 3982336);          //    131,072 B
    float* part = (float*)(base + 4113408);          //  8,388,608 B (~12.5 MB)

    void* args[] = {
        (void*)&x, (void*)&Wq, (void*)&bq, (void*)&Wk, (void*)&bk,
        (void*)&Wv, (void*)&bv, (void*)&out, (void*)&Wt, (void*)&bcat,
        (void*)&gq, (void*)&gk, (void*)&vt, (void*)&l2, (void*)&part
    };
    hipError_t err = hipLaunchCooperativeKernel(
        (void*)fused_kernel, dim3(512), dim3(256), args, 0, stream);

    if (err != hipSuccess) {
        // Fallback: round-4 five-kernel pipeline (known-good 134.9 us)
        prep_kernel<<<512, 256, 0, stream>>>(Wq, Wk, Wv, bq, bk, bv, Wt, bcat);
        qkv_kernel<<<512, 256, 0, stream>>>(x, Wt, bcat, gq, gk, vt);
        stats_kernel<<<512, 256, 0, stream>>>(gq, gk, l2);
        out_kernel<<<512, 256, 0, stream>>>(gq, gk, vt, l2, part);
        reduce_kernel<<<512, 256, 0, stream>>>(part, out);
    }
}

// Round 7
// 125.646 us; speedup vs baseline: 2.8996x; 2.8996x over previous
//
#include <hip/hip_runtime.h>
#include <math.h>

// (B,N,D,H) = (4, 2048, 1024, 64)
constexpr int kN = 2048;
constexpr int kD = 1024;

typedef __attribute__((ext_vector_type(8))) short bf16x8;
typedef __attribute__((ext_vector_type(4))) short bf16x4;
typedef __attribute__((ext_vector_type(4))) float f32x4;

#define MFMA(a, b, c) __builtin_amdgcn_mfma_f32_16x16x32_bf16(a, b, c, 0, 0, 0)

__device__ __forceinline__ short f2bf(float f) {
    unsigned u = __float_as_uint(f);
    u += 0x7fff + ((u >> 16) & 1);      // round-to-nearest-even
    return (short)(u >> 16);
}
__device__ __forceinline__ float bf2f(short s) {
    return __uint_as_float(((unsigned)(unsigned short)s) << 16);
}

// global->LDS direct DMA. LDS dest = wave-uniform base + lane*16.
__device__ __forceinline__ void g2l(void* lds, const void* g, int nbytes, int t) {
    int lane = t & 63, w = t >> 6;
    for (int base = w * 1024; base < nbytes; base += 4096) {
        if (base + lane * 16 < nbytes) {
            __builtin_amdgcn_global_load_lds(
                (const __attribute__((address_space(1))) void*)((const char*)g + base + lane * 16),
                (__attribute__((address_space(3))) void*)((char*)lds + base),
                16, 0, 0);
        }
    }
}

// ---------------------------------------------------------------------------
// prep: Wt in MFMA-fragment-contiguous layout:
//   Wt[((kc*12 + nt)*2 + f)*512 + lane*8 + e]  holds  W^T[n][d] as bf16
//   with n = nt*16 + (lane&15), d = kc*64 + f*32 + (lane>>4)*8 + e.
// One wave B-fragment load = 64 lanes x 16 B contiguous (1 KB coalesced).
// bcat = bq|bk|bv.
// ---------------------------------------------------------------------------
__global__ __launch_bounds__(256) void prep_kernel(
        const float* __restrict__ Wq, const float* __restrict__ Wk,
        const float* __restrict__ Wv, const float* __restrict__ bq,
        const float* __restrict__ bk, const float* __restrict__ bv,
        short* __restrict__ Wt, float* __restrict__ bcat)
{
    int tid = blockIdx.x * 256 + threadIdx.x;
    int stride = gridDim.x * 256;
    for (int e = tid; e < 16 * 12 * 2 * 512; e += stride) {
        int kc = e / 12288;
        int rem = e - kc * 12288;
        int nt = rem >> 10;
        int r2 = rem & 1023;
        int f = r2 >> 9;
        int r3 = r2 & 511;
        int q8 = r3 >> 7;
        int l15 = (r3 >> 3) & 15;
        int el = r3 & 7;
        int n = nt * 16 + l15;
        int d = kc * 64 + f * 32 + q8 * 8 + el;
        float wv = (n < 64) ? Wq[d * 64 + n]
                 : (n < 128) ? Wk[d * 64 + (n - 64)]
                 : Wv[d * 64 + (n - 128)];
        Wt[e] = f2bf(wv);
    }
    if (tid < 192)
        bcat[tid] = (tid < 64) ? bq[tid] : (tid < 128) ? bk[tid - 64] : bv[tid - 128];
}

// ---------------------------------------------------------------------------
// qkv: [8192x1024]@[1024x192]. 512 blocks x 16 rows. x-tile staged to LDS
// ONCE (no inner barriers); W fragments loaded direct global->VGPR (coalesced,
// L2-resident). Wave w = cols [48w, 48w+48).
// Outputs: gq/gk[8192][72] bf16, vt[(bz*32+jt)*64+h][72] bf16 (j-local cols).
// ---------------------------------------------------------------------------
constexpr int XP = 1032;   // xs pitch (shorts): stride 516 words = 4 mod 32 banks

__global__ __launch_bounds__(256) void qkv_kernel(
        const float* __restrict__ x, const short* __restrict__ Wt,
        const float* __restrict__ bcat,
        short* __restrict__ gq, short* __restrict__ gk, short* __restrict__ vt)
{
    __shared__ __align__(16) short xs[16 * XP];    // 33,024 B
    const int t = threadIdx.x;
    const int w = t >> 6, lane = t & 63, l15 = lane & 15, q8 = lane >> 4;
    const int m0 = blockIdx.x * 16;

    // stage x tile (16 rows x 1024), fp32 -> bf16, once
    {
        int row = t >> 4, c4 = (t & 15) * 4;
        const float* xr = x + (size_t)(m0 + row) * kD;
        #pragma unroll
        for (int cc = 0; cc < 16; ++cc) {
            float4 xv = *(const float4*)&xr[cc * 64 + c4];
            bf16x4 pk = {f2bf(xv.x), f2bf(xv.y), f2bf(xv.z), f2bf(xv.w)};
            *(bf16x4*)&xs[row * XP + cc * 64 + c4] = pk;
        }
    }
    __syncthreads();

    f32x4 acc[3];
    #pragma unroll
    for (int ct = 0; ct < 3; ++ct) acc[ct] = (f32x4){0.f, 0.f, 0.f, 0.f};

    #pragma unroll 4
    for (int kc = 0; kc < 16; ++kc) {
        bf16x8 a0 = *(const bf16x8*)&xs[l15 * XP + kc * 64 + q8 * 8];
        bf16x8 a1 = *(const bf16x8*)&xs[l15 * XP + kc * 64 + 32 + q8 * 8];
        #pragma unroll
        for (int ct = 0; ct < 3; ++ct) {
            int nt = w * 3 + ct;
            const short* bp = Wt + ((size_t)(kc * 12 + nt) * 2) * 512 + lane * 8;
            bf16x8 b0 = *(const bf16x8*)bp;
            bf16x8 b1 = *(const bf16x8*)(bp + 512);
            acc[ct] = MFMA(a0, b0, acc[ct]);
            acc[ct] = MFMA(a1, b1, acc[ct]);
        }
    }

    const int bz = m0 >> 11;
    const int jt = (m0 & 2047) >> 6;
    const int jb = m0 & 63;                // 0/16/32/48
    #pragma unroll
    for (int ct = 0; ct < 3; ++ct) {
        int nb2 = w * 48 + ct * 16;        // 16-tile lies in one region
        int n = nb2 + l15;
        float bias = bcat[n];
        if (nb2 < 64) {
            #pragma unroll
            for (int r = 0; r < 4; ++r)
                gq[(size_t)(m0 + q8 * 4 + r) * 72 + n] = f2bf(acc[ct][r] + bias);
        } else if (nb2 < 128) {
            #pragma unroll
            for (int r = 0; r < 4; ++r)
                gk[(size_t)(m0 + q8 * 4 + r) * 72 + (n - 64)] = f2bf(acc[ct][r] + bias);
        } else {
            int h = n - 128;
            bf16x4 pk = {f2bf(acc[ct][0] + bias), f2bf(acc[ct][1] + bias),
                         f2bf(acc[ct][2] + bias), f2bf(acc[ct][3] + bias)};
            *(bf16x4*)&vt[((size_t)((bz * 32 + jt) * 64 + h)) * 72 + jb + q8 * 4] = pk;
        }
    }
}

// ---------------------------------------------------------------------------
// stats: l[j] = sum_{i>=j, s!=0} exp(s/8). Double-buffered k tiles.
// Grid 512: b&3 = i-chunk(512), (b>>2)&3 = bz, b>>4 = j-tile(64). Max 8 iters.
// ---------------------------------------------------------------------------
__global__ __launch_bounds__(256) void stats_kernel(
        const short* __restrict__ gq, const short* __restrict__ gk,
        float* __restrict__ l2)
{
    __shared__ __align__(16) short qsm[64 * 72];
    __shared__ __align__(16) short ksm[2][64 * 72];
    const int t = threadIdx.x;
    const int w = t >> 6, lane = t & 63, l15 = lane & 15, q8 = lane >> 4;
    const int b = blockIdx.x;
    const int ic = b & 3, bz = (b >> 2) & 3, jt = b >> 4;
    const int j0 = jt * 64;
    const int ilo = ic * 512, ihi = ilo + 512;
    const int istart = (j0 > ilo) ? j0 : ilo;
    const int count = (istart < ihi) ? ((ihi - istart) >> 6) : 0;

    float lloc[4] = {0.f, 0.f, 0.f, 0.f};

    if (count > 0) {
        g2l(qsm, gq + (size_t)(bz * kN + j0) * 72, 64 * 144, t);
        g2l(ksm[0], gk + (size_t)(bz * kN + istart) * 72, 64 * 144, t);
        __syncthreads();
        int jrow = 16 * w + l15;
        bf16x8 a0 = *(const bf16x8*)&qsm[jrow * 72 + q8 * 8];
        bf16x8 a1 = *(const bf16x8*)&qsm[jrow * 72 + 32 + q8 * 8];

        for (int idx = 0; idx < count; ++idx) {
            const int cur = idx & 1;
            if (idx + 1 < count)
                g2l(ksm[cur ^ 1],
                    gk + (size_t)(bz * kN + istart + (idx + 1) * 64) * 72, 64 * 144, t);
            const int i0 = istart + idx * 64;
            #pragma unroll
            for (int it = 0; it < 4; ++it) {
                int irow = it * 16 + l15;
                bf16x8 b0 = *(const bf16x8*)&ksm[cur][irow * 72 + q8 * 8];
                bf16x8 b1 = *(const bf16x8*)&ksm[cur][irow * 72 + 32 + q8 * 8];
                f32x4 s = (f32x4){0.f, 0.f, 0.f, 0.f};
                s = MFMA(a0, b0, s);
                s = MFMA(a1, b1, s);
                int ig = i0 + it * 16 + l15;
                #pragma unroll
                for (int r = 0; r < 4; ++r) {
                    int jg = j0 + 16 * w + q8 * 4 + r;
                    float sv = s[r];
                    float e = __expf(sv * 0.125f);
                    lloc[r] += ((ig >= jg) && (sv != 0.0f)) ? e : 0.0f;
                }
            }
            __syncthreads();
        }
    }
    #pragma unroll
    for (int off = 1; off < 16; off <<= 1)
        #pragma unroll
        for (int r = 0; r < 4; ++r)
            lloc[r] += __shfl_xor(lloc[r], off);
    if (l15 == 0) {
        #pragma unroll
        for (int r = 0; r < 4; ++r)
            l2[ic * 8192 + bz * kN + j0 + 16 * w + q8 * 4 + r] = lloc[r];
    }
}

// ---------------------------------------------------------------------------
// vscale: vt[j,h] *= 1/l[j] in place (folds softmax denominator into V).
// Grid 128 = (bz*32+jt); rows g*64+h, cols jb (j-local).
// ---------------------------------------------------------------------------
__global__ __launch_bounds__(256) void vscale_kernel(
        short* __restrict__ vt, const float* __restrict__ l2)
{
    __shared__ float rsm[64];
    const int g = blockIdx.x, t = threadIdx.x;
    if (t < 64) {
        int j = (g >> 5) * kN + (g & 31) * 64 + t;
        float l = l2[j] + l2[8192 + j] + l2[16384 + j] + l2[24576 + j];
        rsm[t] = (l > 0.f) ? 1.0f / l : 0.0f;
    }
    __syncthreads();
    const int h = t >> 2, c0 = (t & 3) * 16;
    size_t base = ((size_t)g * 64 + h) * 72 + c0;
    #pragma unroll
    for (int bb = 0; bb < 2; ++bb) {
        bf16x8 v = *(bf16x8*)&vt[base + bb * 8];
        bf16x8 o;
        #pragma unroll
        for (int e = 0; e < 8; ++e)
            o[e] = f2bf(bf2f(v[e]) * rsm[c0 + bb * 8 + e]);
        *(bf16x8*)&vt[base + bb * 8] = o;
    }
}

// ---------------------------------------------------------------------------
// out: partial[i,h] = sum_{j in jc-chunk, j<=i} exp(s/8) * vtilde[j,h]
// Grid 512: b&3 = jc(512-chunk), (b>>2)&3 = bz, b>>4 = i-tile(64). Max 8 iters.
// q/v double-buffered; S recomputed with bit-identical MFMA sequence as stats.
// ---------------------------------------------------------------------------
__global__ __launch_bounds__(256) void out_kernel(
        const short* __restrict__ gq, const short* __restrict__ gk,
        const short* __restrict__ vt, float* __restrict__ part)
{
    __shared__ __align__(16) short ksm[64 * 72];
    __shared__ __align__(16) short qsm[2][64 * 72];
    __shared__ __align__(16) short vsm[2][64 * 72];
    __shared__ __align__(16) short psm[64 * 72];
    const int t = threadIdx.x;
    const int w = t >> 6, lane = t & 63, l15 = lane & 15, q8 = lane >> 4;
    const int b = blockIdx.x;
    const int jc = b & 3, bz = (b >> 2) & 3, it = b >> 4;
    const int i0 = it * 64;
    const int jlo = jc * 512;
    const int jhi = (jlo + 512 < i0 + 64) ? (jlo + 512) : (i0 + 64);
    const int count = (jlo < jhi) ? ((jhi - jlo) >> 6) : 0;

    f32x4 oacc[4];
    #pragma unroll
    for (int i = 0; i < 4; ++i) oacc[i] = (f32x4){0.f, 0.f, 0.f, 0.f};

    if (count > 0) {
        g2l(ksm, gk + (size_t)(bz * kN + i0) * 72, 64 * 144, t);
        g2l(qsm[0], gq + (size_t)(bz * kN + jlo) * 72, 64 * 144, t);
        g2l(vsm[0], vt + (size_t)((bz * 32 + (jlo >> 6)) * 64) * 72, 64 * 144, t);
        __syncthreads();

        for (int idx = 0; idx < count; ++idx) {
            const int cur = idx & 1, nb = cur ^ 1;
            const int j0s = jlo + idx * 64;
            if (idx + 1 < count) {
                g2l(qsm[nb], gq + (size_t)(bz * kN + j0s + 64) * 72, 64 * 144, t);
                g2l(vsm[nb], vt + (size_t)((bz * 32 + ((j0s + 64) >> 6)) * 64) * 72,
                    64 * 144, t);
            }
            // S phase (identical sequence to stats)
            int jrow = 16 * w + l15;
            bf16x8 a0 = *(const bf16x8*)&qsm[cur][jrow * 72 + q8 * 8];
            bf16x8 a1 = *(const bf16x8*)&qsm[cur][jrow * 72 + 32 + q8 * 8];
            #pragma unroll
            for (int itile = 0; itile < 4; ++itile) {
                int irow = itile * 16 + l15;
                bf16x8 b0 = *(const bf16x8*)&ksm[irow * 72 + q8 * 8];
                bf16x8 b1 = *(const bf16x8*)&ksm[irow * 72 + 32 + q8 * 8];
                f32x4 sv4 = (f32x4){0.f, 0.f, 0.f, 0.f};
                sv4 = MFMA(a0, b0, sv4);
                sv4 = MFMA(a1, b1, sv4);
                int ig = i0 + itile * 16 + l15;
                bf16x4 pk;
                #pragma unroll
                for (int r = 0; r < 4; ++r) {
                    int jg = j0s + 16 * w + q8 * 4 + r;
                    float sv = sv4[r];
                    float p = ((ig >= jg) && (sv != 0.0f)) ? __expf(sv * 0.125f) : 0.0f;
                    pk[r] = f2bf(p);
                }
                *(bf16x4*)&psm[(itile * 16 + l15) * 72 + 16 * w + q8 * 4] = pk;
            }
            __syncthreads();   // psm ready; next-tile g2l had S-phase to fly

            // PV phase: A = psm[i-local][j], B = vsm[h][j] (pre-scaled by 1/l)
            bf16x8 pa0 = *(const bf16x8*)&psm[(16 * w + l15) * 72 + q8 * 8];
            bf16x8 pa1 = *(const bf16x8*)&psm[(16 * w + l15) * 72 + 32 + q8 * 8];
            #pragma unroll
            for (int ht = 0; ht < 4; ++ht) {
                int vrow = ht * 16 + l15;
                bf16x8 vb0 = *(const bf16x8*)&vsm[cur][vrow * 72 + q8 * 8];
                bf16x8 vb1 = *(const bf16x8*)&vsm[cur][vrow * 72 + 32 + q8 * 8];
                oacc[ht] = MFMA(pa0, vb0, oacc[ht]);
                oacc[ht] = MFMA(pa1, vb1, oacc[ht]);
            }
            __syncthreads();   // protect psm + qsm[cur]/vsm[cur] for next iter
        }
    }
    size_t base = ((size_t)(jc * 4 + bz) * kN + i0) * 64;
    #pragma unroll
    for (int ht = 0; ht < 4; ++ht)
        #pragma unroll
        for (int r = 0; r < 4; ++r)
            part[base + (size_t)(16 * w + q8 * 4 + r) * 64 + ht * 16 + l15] = oacc[ht][r];
}

// ---------------------------------------------------------------------------
// reduce: out = sum of 4 jc-chunk partials
// ---------------------------------------------------------------------------
__global__ __launch_bounds__(256) void reduce_kernel(
        const float* __restrict__ part, float* __restrict__ out)
{
    int idx = blockIdx.x * 256 + threadIdx.x;     // 0..131071 float4s
    const float4* p = (const float4*)part;
    float4 a = p[idx];
    float4 b = p[idx + 131072];
    float4 c = p[idx + 262144];
    float4 d = p[idx + 393216];
    float4 r;
    r.x = a.x + b.x + c.x + d.x;
    r.y = a.y + b.y + c.y + d.y;
    r.z = a.z + b.z + c.z + d.z;
    r.w = a.w + b.w + c.w + d.w;
    ((float4*)out)[idx] = r;
}

extern "C" void kernel_launch(void* const* d_in, const int* in_sizes, int n_in,
                              void* d_out, int out_size, void* d_ws, size_t ws_size,
                              hipStream_t stream)
{
    const float* x  = (const float*)d_in[0];
    const float* Wq = (const float*)d_in[1];
    const float* bq = (const float*)d_in[2];
    const float* Wk = (const float*)d_in[3];
    const float* bk = (const float*)d_in[4];
    const float* Wv = (const float*)d_in[5];
    const float* bv = (const float*)d_in[6];
    float* out = (float*)d_out;

    char* base = (char*)d_ws;
    short* Wt   = (short*)(base);                    //    393,216 B
    float* bcat = (float*)(base + 393216);           //      1,024 B
    short* gq   = (short*)(base + 394240);           //  1,179,648 B
    short* gk   = (short*)(base + 1573888);          //  1,179,648 B
    short* vt   = (short*)(base + 2753536);          //  1,179,648 B
    float* l2   = (float*)(base + 3933184);          //    131,072 B
    float* part = (float*)(base + 4064256);          //  8,388,608 B (~12.5 MB)

    prep_kernel<<<256, 256, 0, stream>>>(Wq, Wk, Wv, bq, bk, bv, Wt, bcat);
    qkv_kernel<<<512, 256, 0, stream>>>(x, Wt, bcat, gq, gk, vt);
    stats_kernel<<<512, 256, 0, stream>>>(gq, gk, l2);
    vscale_kernel<<<128, 256, 0, stream>>>(vt, l2);
    out_kernel<<<512, 256, 0, stream>>>(gq, gk, vt, part);
    reduce_kernel<<<512, 256, 0, stream>>>(part, out);
}